// Round 21
// baseline (33.295 us; speedup 1.0000x reference)
//
#include <hip/hip_runtime.h>
#include <math.h>

#define B_ 32
#define P_ 1000
#define T_ 16
#define D_ 78
#define O_ 72
#define NXB 16            // p-chunks of 64
#define BIGC 100000000.0f

// ---------------- K1: masked-L1 sums S + per-p scalars + per-block partial maxes ----------------
// 1024 threads = 16 waves; wave wv handles t = wv over the full o-loop.
// 512 blocks x 16 waves pack 2 blocks/CU -> 32 waves/CU (full occupancy; round-20's
// 512-thr was 16). tomg = NaN-folded float per (t,o), linear [t][o]; wave reads its
// row via b128 broadcasts (4 o's per read, consumed in ascending-o order -> S chain
// bit-identical to rounds 18-20).
__global__ __launch_bounds__(1024) void k1(
        const float* __restrict__ preds, const float* __restrict__ targets,
        const int* __restrict__ imgw_p, const int* __restrict__ imgh_p,
        float* __restrict__ Sarr, float4* __restrict__ scal4, float* __restrict__ pths,
        float* __restrict__ pmax, float* __restrict__ cntg) {
    __shared__ float pred_s[64 * 81];          // 20.7 KB, pad 81 -> conflict-free rows
    __shared__ __align__(16) float tomg[T_ * O_];  // 4.6 KB  [t*O + o] = to' (NaN if invalid)
    __shared__ float wmax[16][3];
    __shared__ float cnt_s[T_], clen_s[T_], ts0_s[T_], ts1_s[T_], tth_s[T_];

    const int b = blockIdx.y, bx = blockIdx.x;
    const int p0 = bx * 64;
    const int rows = min(64, P_ - p0);
    const int tid = threadIdx.x;
    const float w = (float)(imgw_p[0] - 1);
    const float h = (float)(imgh_p[0] - 1);
    const float imgwf = (float)imgw_p[0];

    // stage preds rows (coalesced float4); scale col 3 and cols>=6 by w
    {
        const float4* gbase = (const float4*)(preds + ((size_t)b * P_ + p0) * D_);
        const int n4 = rows * D_ / 4;
        for (int i = tid; i < n4; i += 1024) {
            float4 v = gbase[i];
            int base = i * 4;
            int r = base / D_, c = base - r * D_;
#pragma unroll
            for (int k = 0; k < 4; ++k) {
                int cc = c + k, rr = r;
                if (cc >= D_) { cc -= D_; ++rr; }
                float x = (&v.x)[k];
                if (cc >= 6 || cc == 3) x *= w;
                pred_s[rr * 81 + cc] = x;
            }
        }
    }
    // stage target offsets: to*w if valid else NaN, linear [t][o]
    for (int i = tid; i < T_ * O_; i += 1024) {
        int t = i / O_, o = i - t * O_;
        float to = targets[((size_t)b * T_ + t) * D_ + 6 + o] * w;
        bool valid = (to >= 0.f) && (to < imgwf);
        tomg[t * O_ + o] = valid ? to : __int_as_float(0x7fc00000);
    }
    __syncthreads();
    if (tid < T_) {
        int t = tid;
        float c = 0.f;
        for (int o = 0; o < O_; ++o) {
            float to = tomg[t * O_ + o];
            c += (to == to) ? 1.f : 0.f;       // !isnan == valid
        }
        cnt_s[t] = c;
        clen_s[t] = fmaxf(c, 1.f);
        const float* tr = targets + ((size_t)b * T_ + t) * D_;
        ts0_s[t] = tr[2] * h;
        ts1_s[t] = tr[3] * w;
        tth_s[t] = tr[4];
    }
    __syncthreads();

    if (bx == 0 && tid < T_) cntg[b * T_ + tid] = cnt_s[tid];

    const int lane = tid & 63;
    const int wv = tid >> 6;                   // wave = t: t = wv (0..15)
    const int p = p0 + lane;

    float ldm = 0.f, lsm = 0.f, ltm = 0.f;
    if (p < P_) {
        const float* lrow = pred_s + lane * 81;
        const float4* trow4 = (const float4*)(tomg + wv * O_);   // 16B-aligned (O_=72)
        float S = 0.f;
#pragma unroll
        for (int oq = 0; oq < O_ / 4; ++oq) {
            float4 tv = trow4[oq];             // 4 o's, wave-uniform broadcast
#pragma unroll
            for (int k = 0; k < 4; ++k) {      // ascending o -> chain order preserved
                float po = lrow[6 + 4 * oq + k];
                S += fmaxf(fabsf(po - (&tv.x)[k]), 0.f);   // NaN -> 0 (IEEE max)
            }
        }
        const int t = wv;
        Sarr[(size_t)(b * T_ + t) * P_ + p] = S;
        float dv = S / clen_s[t];              // needed only for the dist-max
        ldm = dv;
        float ps0 = lrow[2] * h, ps1 = lrow[3], pth = lrow[4];   // col3 pre-scaled by w
        float d0 = ps0 - ts0_s[t], d1 = ps1 - ts1_s[t];
        lsm = sqrtf(d0 * d0 + d1 * d1);
        ltm = fabsf(pth - tth_s[t]) * 180.f;
        if (wv == 0) {                         // per-p scalars for K2
            float fc[2];
#pragma unroll
            for (int c = 0; c < 2; ++c) {
                float x = lrow[c];
                float pc = 1.f / (1.f + expf(-x));
                float neg = -logf(1.f - pc + 1e-12f) * 0.75f * pc * pc;
                float pos = -logf(pc + 1e-12f) * 0.25f * (1.f - pc) * (1.f - pc);
                fc[c] = pos - neg;
            }
            scal4[(size_t)b * P_ + p] = make_float4(fc[0], fc[1], ps0, ps1);
            pths[(size_t)b * P_ + p] = pth;
        }
    }

    // per-wave shuffle max (fmax order-invariant -> exact), tiny merge
    for (int off = 32; off; off >>= 1) {
        ldm = fmaxf(ldm, __shfl_xor(ldm, off, 64));
        lsm = fmaxf(lsm, __shfl_xor(lsm, off, 64));
        ltm = fmaxf(ltm, __shfl_xor(ltm, off, 64));
    }
    if (lane == 0) { wmax[wv][0] = ldm; wmax[wv][1] = lsm; wmax[wv][2] = ltm; }
    __syncthreads();
    if (tid == 0) {
        float m0 = 0.f, m1 = 0.f, m2 = 0.f;
#pragma unroll
        for (int i = 0; i < 16; ++i) {
            m0 = fmaxf(m0, wmax[i][0]);
            m1 = fmaxf(m1, wmax[i][1]);
            m2 = fmaxf(m2, wmax[i][2]);
        }
        float* q = pmax + (size_t)(b * NXB + bx) * 3;
        q[0] = m0; q[1] = m1; q[2] = m2;
    }
}

// ---------------- K2: block per (b,t) — vectorized phase 0, wave-0 LDS-scan top-4 ----------------
// (byte-identical to rounds 19/20 — verified)
__global__ __launch_bounds__(256) void k2(
        const float* __restrict__ targets, const int* __restrict__ masks,
        const int* __restrict__ imgw_p, const int* __restrict__ imgh_p,
        const float* __restrict__ Sarr,
        const float4* __restrict__ scal4, const float* __restrict__ pths,
        const float* __restrict__ pmax, const float* __restrict__ cntg,
        int4* __restrict__ sel, float4* __restrict__ selc) {
    __shared__ __align__(16) float costL[1024];
    __shared__ __align__(16) float SL[1024];

    const int wid = blockIdx.x;              // (b,t)
    const int b = wid >> 4, t = wid & 15;
    const int tid = threadIdx.x;

    const int mk = masks[b * T_ + t];
    if (mk <= 0) {                           // block-uniform: no barrier divergence
        if (tid == 0) {
            sel[wid]  = make_int4(-1, -1, -1, -1);
            selc[wid] = make_float4(BIGC, BIGC, BIGC, BIGC);
        }
        return;
    }

    float dm = 0.f, sm = 0.f, tm = 0.f;
    for (int i = 0; i < NXB; ++i) {
        const float* q = pmax + (size_t)(b * NXB + i) * 3;
        dm = fmaxf(dm, q[0]); sm = fmaxf(sm, q[1]); tm = fmaxf(tm, q[2]);
    }
    dm = fmaxf(dm, 1e-8f); sm = fmaxf(sm, 1e-8f); tm = fmaxf(tm, 1e-8f);

    const float w = (float)(imgw_p[0] - 1);
    const float h = (float)(imgh_p[0] - 1);
    const float* tr = targets + (size_t)(b * T_ + t) * D_;
    const float ts0 = tr[2] * h, ts1 = tr[3] * w, tth = tr[4];
    int lab = (int)tr[1]; lab = lab < 0 ? 0 : (lab > 1 ? 1 : lab);
    const float cntv = cntg[b * T_ + t];
    const float clen = fmaxf(cntv, 1.f);
    const float c30 = 30.f * cntv;

    const float4* S4  = (const float4*)(Sarr + (size_t)(b * T_ + t) * P_);   // 4000B rows, 16B-aligned
    const float4* pt4 = (const float4*)(pths + (size_t)b * P_);
    const float4* s4b = scal4 + (size_t)b * P_;
    float4* costL4 = (float4*)costL;
    float4* SL4    = (float4*)SL;

    // ---- phase 0: 250 threads x 4 consecutive p, vectorized ----
    if (tid < 250) {
        float4 Sv   = S4[tid];
        float4 pthv = pt4[tid];
        float4 cv, sv;
#pragma unroll
        for (int k = 0; k < 4; ++k) {
            float S   = (&Sv.x)[k];
            float4 s4 = s4b[4 * tid + k];
            float pth = (&pthv.x)[k];
            float dv = S / clen;                      // == k1's dist, bit-identical
            float dsc = 1.f - dv / dm + 0.01f;
            float d0 = s4.z - ts0, d1 = s4.w - ts1;
            float ssc = 1.f - sqrtf(d0 * d0 + d1 * d1) / sm + 0.01f;
            float tsc = 1.f - fabsf(pth - tth) * 180.f / tm + 0.01f;
            float reg = fmaxf(dsc, 1e-3f) * fmaxf(ssc, 1e-3f) * fmaxf(tsc, 1e-3f);
            float c = -(reg * reg) * 3.f + (lab ? s4.y : s4.x);
            (&cv.x)[k] = c;                           // mk>0 here: no BIGC override
            (&sv.x)[k] = S;
        }
        costL4[tid] = cv;
        SL4[tid] = sv;
    } else {
        costL4[tid] = make_float4(INFINITY, INFINITY, INFINITY, INFINITY);
        SL4[tid]    = make_float4(INFINITY, INFINITY, INFINITY, INFINITY);
    }
    __syncthreads();
    if (tid >= 64) return;                   // wave 0 finishes alone

    const int lane = tid;

    // bottom-4 S ascending == top-4 liou descending (liou monotone-dec in S)
    float v0, v1, v2, v3;
#define SROUND(vr) { float bv = INFINITY; int bi = 0x7fffffff;            \
        _Pragma("unroll")                                                 \
        for (int i = 0; i < 16; ++i) { int ix = lane + 64 * i;            \
            float v = SL[ix];                                             \
            if (v < bv || (v == bv && ix < bi)) { bv = v; bi = ix; } }    \
        for (int off = 32; off; off >>= 1) {                              \
            float ov = __shfl_xor(bv, off, 64);                           \
            int oi = __shfl_xor(bi, off, 64);                             \
            if (ov < bv || (ov == bv && oi < bi)) { bv = ov; bi = oi; }   \
        }                                                                 \
        vr = bv; if ((bi & 63) == lane) SL[bi] = INFINITY; }
    SROUND(v0) SROUND(v1) SROUND(v2) SROUND(v3)
#undef SROUND
    float l0 = (c30 - v0) / (c30 + v0 + 1e-9f);
    float l1 = (c30 - v1) / (c30 + v1 + 1e-9f);
    float l2 = (c30 - v2) / (c30 + v2 + 1e-9f);
    float l3 = (c30 - v3) / (c30 + v3 + 1e-9f);
    float sum = ((l0 + l1) + l2) + l3;
    int dk = (int)sum;                 // trunc toward zero == astype(int32)
    if (dk < 1) dk = 1;
    if (dk > 4) dk = 4;

    // top-4 lowest cost (asc, lower-p tie-break == lax.top_k stable)
    int s0, s1, s2, s3;
    float c0, c1, c2, c3;
#define CROUND(sr, cr) { float bv = INFINITY; int bi = 0x7fffffff;        \
        _Pragma("unroll")                                                 \
        for (int i = 0; i < 16; ++i) { int ix = lane + 64 * i;            \
            float v = costL[ix];                                          \
            if (v < bv || (v == bv && ix < bi)) { bv = v; bi = ix; } }    \
        for (int off = 32; off; off >>= 1) {                              \
            float ov = __shfl_xor(bv, off, 64);                           \
            int oi = __shfl_xor(bi, off, 64);                             \
            if (ov < bv || (ov == bv && oi < bi)) { bv = ov; bi = oi; }   \
        }                                                                 \
        sr = bi; cr = bv; if ((bi & 63) == lane) costL[bi] = INFINITY; }
    CROUND(s0, c0) CROUND(s1, c1) CROUND(s2, c2) CROUND(s3, c3)
#undef CROUND

    if (lane == 0) {
        sel[wid]  = make_int4(dk > 0 ? s0 : -1, dk > 1 ? s1 : -1,
                              dk > 2 ? s2 : -1, dk > 3 ? s3 : -1);
        selc[wid] = make_float4(c0, c1, c2, c3);
    }
}

// ---------------- K3: membership + conflict resolution from sel/selc only ----------------
__global__ __launch_bounds__(256) void k3(const int* __restrict__ sel,
                                          const float* __restrict__ selc,
                                          int* __restrict__ out) {
    __shared__ int selE[64];
    __shared__ float selC[64];
    const int b = blockIdx.y, cx = blockIdx.x;
    if (threadIdx.x < 64) {
        selE[threadIdx.x] = sel[b * 64 + threadIdx.x];
        selC[threadIdx.x] = selc[b * 64 + threadIdx.x];
    }
    __syncthreads();

    const int p = cx * 250 + threadIdx.x;
    if (threadIdx.x < 250) {
        int matched = -1;
        float best = INFINITY;
#pragma unroll
        for (int t = 0; t < T_; ++t) {
#pragma unroll
            for (int j = 0; j < 4; ++j) {
                if (selE[4 * t + j] == p) {
                    float c = selC[4 * t + j];
                    if (c < best) { best = c; matched = t; }  // strict <: first-min on t
                }
            }
        }
        out[b * P_ + p] = (matched >= 0) ? 1 : 0;
        out[B_ * P_ + b * P_ + p] = matched;
    }
}

extern "C" void kernel_launch(void* const* d_in, const int* in_sizes, int n_in,
                              void* d_out, int out_size, void* d_ws, size_t ws_size,
                              hipStream_t stream) {
    const float* preds   = (const float*)d_in[0];
    const float* targets = (const float*)d_in[1];
    const int*   masks   = (const int*)d_in[2];
    const int*   imgw    = (const int*)d_in[3];
    const int*   imgh    = (const int*)d_in[4];
    int* out = (int*)d_out;

    char* ws = (char*)d_ws;
    float*  Sarr  = (float*)ws;                        // [B][T][P]  2,048,000 B
    float4* scal4 = (float4*)(ws + 2048000);           // [B][P]       512,000 B
    float*  pths  = (float*)(ws + 2560000);            // [B][P]       128,000 B
    float*  pmax  = (float*)(ws + 2688000);            // [B][NXB][3]    6,144 B
    float*  cntg  = (float*)(ws + 2694144);            // [B][T]         2,048 B
    int4*   sel   = (int4*)(ws + 2696192);             // [B*T]          8,192 B
    float4* selc  = (float4*)(ws + 2704384);           // [B*T]          8,192 B

    k1<<<dim3(NXB, B_), 1024, 0, stream>>>(preds, targets, imgw, imgh,
                                           Sarr, scal4, pths, pmax, cntg);
    k2<<<B_ * T_, 256, 0, stream>>>(targets, masks, imgw, imgh, Sarr, scal4, pths,
                                    pmax, cntg, sel, selc);
    k3<<<dim3(4, B_), 256, 0, stream>>>((const int*)sel, (const float*)selc, out);
}